// Round 8
// baseline (127.900 us; speedup 1.0000x reference)
//
#include <hip/hip_runtime.h>

// SkeletonConv: out[b,o,h,w] = sum_{c,k} W[o,c,k] * x[b,c, h+(k-1)*step, w+(k-1)*dil]
// B=64, C_in=C_out=16, K=3, H=W=256, fp32.
// R8: R7 structure + v_pk_fma_f32 (packed fp32, 2 FMA/instr, full rate on CDNA).
//     Pairs = adjacent w outputs; taps = 5 shifted f2 pairs; weight = SGPR-pair
//     {w,w} via s_load_dwordx2 from a repacked copy in d_ws (tiny repack kernel).
//     Halves FMA issue: ~96 pk + 12 mov per c -> VALU busy ~25us, memory-bound.
//     Ledger: R1 157 / R2 2660 spill / R3 272 / R4 477 / R5 387 LDS / R6 148
//             AGPR-shuttle / R7 114.7 (cap 128 + fmaf).

constexpr int CIN = 16, COUT = 16, KK = 3, H = 256, W = 256;
constexpr int WT  = 4;            // w-elements per thread (float4)
constexpr int TPR = W / WT;       // 64 threads = one wave per (b,h) row
constexpr int CHUNK = 4;          // c-channels per pipeline stage

typedef float f4 __attribute__((ext_vector_type(4)));
typedef float f2 __attribute__((ext_vector_type(2)));

// Repack W[o][c][k] (fp32) -> wp2[(c*3+k)*16 + o] = {w, w} so the main kernel
// gets the VOP3P weight operand with a single s_load_dwordx2.
__global__ __launch_bounds__(256)
void repack_w_kernel(const float* __restrict__ wgt, f2* __restrict__ wp2) {
    const int t = blockIdx.x * blockDim.x + threadIdx.x;
    if (t < COUT * CIN * KK) {
        const int o  = t / (CIN * KK);
        const int ck = t % (CIN * KK);
        const float w = wgt[t];
        wp2[ck * COUT + o] = f2{w, w};
    }
}

__global__ __launch_bounds__(256, 4)   // VGPR cap 128 (R6: default cap 64 = shuttle)
void skel_conv_kernel(const float* __restrict__ x, const f2* __restrict__ wp2,
                      const float* __restrict__ wgt,
                      const int* __restrict__ dil_p, const int* __restrict__ step_p,
                      float* __restrict__ out, int B)
{
    const int dil  = dil_p[0];
    const int step = step_p[0];

    const int tid  = blockIdx.x * blockDim.x + threadIdx.x;
    const int lane = tid & (TPR - 1);            // lane-in-wave; wave spans a row
    const int idx  = tid / TPR;
    const int h    = idx & (H - 1);
    const int b    = idx >> 8;
    if (b >= B) return;
    const int w0 = lane * WT;

    f2 acc2[COUT][2];                            // {w0,w1},{w2,w3} per out channel
    #pragma unroll
    for (int o = 0; o < COUT; ++o) {
        acc2[o][0] = f2{0.f, 0.f};
        acc2[o][1] = f2{0.f, 0.f};
    }

    const size_t cs = (size_t)H * W;
    const float* xr = x + (size_t)b * CIN * cs + (size_t)h * W + w0;

    if (dil == 1 && step == 0) {
        const bool l0 = (lane == 0), lN = (lane == TPR - 1);

        auto compute_c = [&](int c, f4 v) {      // c is wave-uniform
            float left  = __shfl_up(v.w, 1);     // x[w0-1]
            float right = __shfl_down(v.x, 1);   // x[w0+4]
            if (l0) left  = 0.f;                 // zero padding
            if (lN) right = 0.f;
            // shifted tap pairs: P[i] = {t[i], t[i+1]}, t = {L,x,y,z,w,R}
            const f2 P0 = f2{left, v.x};
            const f2 P1 = f2{v.x,  v.y};
            const f2 P2 = f2{v.y,  v.z};
            const f2 P3 = f2{v.z,  v.w};
            const f2 P4 = f2{v.w,  right};
            const f2* wc = wp2 + (size_t)c * KK * COUT;    // uniform -> s_load
            #pragma unroll
            for (int o = 0; o < COUT; ++o) {
                const f2 wk0 = wc[o];                      // k=0  {w,w}
                const f2 wk1 = wc[COUT + o];               // k=1
                const f2 wk2 = wc[2 * COUT + o];           // k=2
                // jp0 = outputs (w0,w1): taps P0,P1,P2 ; jp1 = (w2,w3): P2,P3,P4
                asm("v_pk_fma_f32 %0, %1, %2, %0" : "+v"(acc2[o][0]) : "v"(P0), "s"(wk0));
                asm("v_pk_fma_f32 %0, %1, %2, %0" : "+v"(acc2[o][1]) : "v"(P2), "s"(wk0));
                asm("v_pk_fma_f32 %0, %1, %2, %0" : "+v"(acc2[o][0]) : "v"(P1), "s"(wk1));
                asm("v_pk_fma_f32 %0, %1, %2, %0" : "+v"(acc2[o][1]) : "v"(P3), "s"(wk1));
                asm("v_pk_fma_f32 %0, %1, %2, %0" : "+v"(acc2[o][0]) : "v"(P2), "s"(wk2));
                asm("v_pk_fma_f32 %0, %1, %2, %0" : "+v"(acc2[o][1]) : "v"(P4), "s"(wk2));
            }
        };

        // prologue: chunk 0 in flight
        f4 p0 = *(const f4*)(xr + 0 * cs);
        f4 p1 = *(const f4*)(xr + 1 * cs);
        f4 p2 = *(const f4*)(xr + 2 * cs);
        f4 p3 = *(const f4*)(xr + 3 * cs);

        #pragma unroll 1
        for (int cc = 0; cc < CIN / CHUNK; ++cc) {
            // issue next chunk's 4 independent loads (last iter re-reads, L1 hit)
            const int nc = (cc + 1 < CIN / CHUNK) ? (cc + 1) * CHUNK : cc * CHUNK;
            const float* nx = xr + (size_t)nc * cs;
            f4 v0 = *(const f4*)(nx + 0 * cs);
            f4 v1 = *(const f4*)(nx + 1 * cs);
            f4 v2 = *(const f4*)(nx + 2 * cs);
            f4 v3 = *(const f4*)(nx + 3 * cs);

            const int cb = cc * CHUNK;
            compute_c(cb + 0, p0);
            compute_c(cb + 1, p1);
            compute_c(cb + 2, p2);
            compute_c(cb + 3, p3);

            p0 = v0; p1 = v1; p2 = v2; p3 = v3;
        }
    } else {
        // Generic path: clamped loads + select (never faults, any dil/step).
        #pragma unroll 1
        for (int c = 0; c < CIN; ++c) {
            const float* xc = x + (size_t)b * CIN * cs + (size_t)c * cs;
            #pragma unroll
            for (int k = 0; k < KK; ++k) {
                const int off = k - KK / 2;
                const int hh  = h + off * step;
                const bool rowok = (hh >= 0) && (hh < H);
                const int hcl = hh < 0 ? 0 : (hh > H - 1 ? H - 1 : hh);
                float t[WT];
                #pragma unroll
                for (int j = 0; j < WT; ++j) {
                    const int ww  = w0 + j + off * dil;
                    const bool ok = rowok && (ww >= 0) && (ww < W);
                    const int wcl = ww < 0 ? 0 : (ww > W - 1 ? W - 1 : ww);
                    const float vv = xc[(size_t)hcl * W + wcl];
                    t[j] = ok ? vv : 0.f;
                }
                #pragma unroll
                for (int o = 0; o < COUT; ++o) {
                    const float wk = wgt[((size_t)o * CIN + c) * KK + k];
                    acc2[o][0].x = fmaf(wk, t[0], acc2[o][0].x);
                    acc2[o][0].y = fmaf(wk, t[1], acc2[o][0].y);
                    acc2[o][1].x = fmaf(wk, t[2], acc2[o][1].x);
                    acc2[o][1].y = fmaf(wk, t[3], acc2[o][1].y);
                }
            }
        }
    }

    float* orow = out + (size_t)b * COUT * cs + (size_t)h * W + w0;
    #pragma unroll
    for (int o = 0; o < COUT; ++o) {
        f4 r = {acc2[o][0].x, acc2[o][0].y, acc2[o][1].x, acc2[o][1].y};
        *(f4*)(orow + (size_t)o * cs) = r;       // coalesced dwordx4
    }
}

extern "C" void kernel_launch(void* const* d_in, const int* in_sizes, int n_in,
                              void* d_out, int out_size, void* d_ws, size_t ws_size,
                              hipStream_t stream) {
    const float* x    = (const float*)d_in[0];
    const float* wgt  = (const float*)d_in[1];
    const int*   dil  = (const int*)d_in[2];
    const int*   step = (const int*)d_in[3];
    float*       out  = (float*)d_out;
    f2*          wp2  = (f2*)d_ws;               // 768 f2 = 6 KB scratch

    repack_w_kernel<<<3, 256, 0, stream>>>(wgt, wp2);

    const int B = in_sizes[0] / (CIN * H * W);
    const int total = B * H * TPR;               // one thread per 4 output w's
    const int block = 256;
    const int grid  = (total + block - 1) / block;

    skel_conv_kernel<<<grid, block, 0, stream>>>(x, wp2, wgt, dil, step, out, B);
}